// Round 1
// baseline (468.749 us; speedup 1.0000x reference)
//
#include <hip/hip_runtime.h>

typedef unsigned short ushort_t;
typedef __attribute__((ext_vector_type(8))) __bf16 bf16x8;
typedef __attribute__((ext_vector_type(4))) float f32x4;

#define NT 8192     // tokens
#define NE 8        // experts
#define ND 1024     // model dim
#define NF 4096     // ffn dim
#define CAP 1280    // capacity per expert

// ws layout (bytes)
#define W1T_OFF 0u                       // 8*4096*1024*2 = 67108864
#define W2T_OFF 67108864u                // 67108864
#define XD_OFF  134217728u               // 10240*1024*2 = 20971520
#define H_OFF   155189248u               // 10240*4096*2 = 83886080
#define EIDX_OFF 239075328u              // 8192*4
#define TPROB_OFF 239108096u             // 8192*4
#define TSLOT_OFF 239140864u             // 10240*4  -> total 239181824

__device__ __forceinline__ unsigned short f2bf(float f) {
  unsigned int u = __float_as_uint(f);
  unsigned int r = (u + 0x7fffu + ((u >> 16) & 1u)) >> 16;
  return (unsigned short)r;
}

// ---------------- zero out ----------------
__global__ void zero_kernel(float* __restrict__ p, long n) {
  long i = (long)blockIdx.x * blockDim.x + threadIdx.x;
  long stride = (long)gridDim.x * blockDim.x;
  float4* p4 = (float4*)p;
  long n4 = n >> 2;
  for (long j = i; j < n4; j += stride) p4[j] = make_float4(0.f, 0.f, 0.f, 0.f);
}

// ---------------- routing: one wave per token ----------------
__global__ void route_kernel(const float* __restrict__ x, const float* __restrict__ gw,
                             const float* __restrict__ gb, int* __restrict__ eidx,
                             float* __restrict__ tprob) {
  int wid = threadIdx.x >> 6, lane = threadIdx.x & 63;
  int t = blockIdx.x * 4 + wid;
  const float4* xv = (const float4*)(x + (size_t)t * ND);
  float acc[NE];
#pragma unroll
  for (int e = 0; e < NE; ++e) acc[e] = 0.f;
#pragma unroll
  for (int c = 0; c < 4; ++c) {
    float4 xx = xv[lane * 4 + c];
#pragma unroll
    for (int e = 0; e < NE; ++e) {
      float4 wv = *(const float4*)(gw + (size_t)e * ND + lane * 16 + c * 4);
      acc[e] += xx.x * wv.x + xx.y * wv.y + xx.z * wv.z + xx.w * wv.w;
    }
  }
#pragma unroll
  for (int off = 32; off >= 1; off >>= 1) {
#pragma unroll
    for (int e = 0; e < NE; ++e) acc[e] += __shfl_xor(acc[e], off, 64);
  }
  if (lane == 0) {
    float l[NE];
#pragma unroll
    for (int e = 0; e < NE; ++e) l[e] = acc[e] + gb[e];
    float mx = l[0];
    int am = 0;
#pragma unroll
    for (int e = 1; e < NE; ++e) {
      if (l[e] > mx) { mx = l[e]; am = e; }   // first occurrence kept on ties
    }
    float s = 0.f;
#pragma unroll
    for (int e = 0; e < NE; ++e) s += __expf(l[e] - mx);
    eidx[t] = am;
    tprob[t] = 1.0f / s;   // softmax prob of the max logit
  }
}

// ---------------- capacity scan (single block, order-preserving) ----------------
__global__ void scan_kernel(const int* __restrict__ eidx, int* __restrict__ tslot) {
  __shared__ unsigned long long s0[1024], s1[1024];
  int tid = threadIdx.x;
  for (int i = tid; i < NE * CAP; i += 1024) tslot[i] = -1;
  int myE[8];
  int loc[NE];
#pragma unroll
  for (int e = 0; e < NE; ++e) loc[e] = 0;
#pragma unroll
  for (int i = 0; i < 8; ++i) {
    int t = tid * 8 + i;
    int e = eidx[t];
    myE[i] = e;
    loc[e]++;
  }
  unsigned long long a = 0, b = 0;
#pragma unroll
  for (int e = 0; e < 4; ++e) {
    a |= ((unsigned long long)(unsigned)loc[e]) << (16 * e);
    b |= ((unsigned long long)(unsigned)loc[4 + e]) << (16 * e);
  }
  s0[tid] = a; s1[tid] = b;
  __syncthreads();
  unsigned long long ia = a, ib = b;
  for (int off = 1; off < 1024; off <<= 1) {
    unsigned long long pa = 0, pb = 0;
    if (tid >= off) { pa = s0[tid - off]; pb = s1[tid - off]; }
    __syncthreads();
    ia += pa; ib += pb;
    s0[tid] = ia; s1[tid] = ib;
    __syncthreads();
  }
  unsigned long long ea = ia - a, eb = ib - b;  // exclusive
  int base[NE];
#pragma unroll
  for (int e = 0; e < 4; ++e) {
    base[e] = (int)((ea >> (16 * e)) & 0xffffULL);
    base[4 + e] = (int)((eb >> (16 * e)) & 0xffffULL);
  }
#pragma unroll
  for (int i = 0; i < 8; ++i) {
    int t = tid * 8 + i;
    int e = myE[i];
    int p = base[e]++;
    if (p < CAP) tslot[e * CAP + p] = t;
  }
}

// ---------------- gather tokens -> bf16 dispatch buffer ----------------
__global__ void gather_kernel(const float* __restrict__ x, const int* __restrict__ tslot,
                              ushort_t* __restrict__ Xd) {
  int slot = blockIdx.x;
  int t = tslot[slot];
  int d = threadIdx.x * 4;
  ushort4 u;
  if (t >= 0) {
    float4 v = *(const float4*)(x + (size_t)t * ND + d);
    u.x = f2bf(v.x); u.y = f2bf(v.y); u.z = f2bf(v.z); u.w = f2bf(v.w);
  } else {
    u.x = 0; u.y = 0; u.z = 0; u.w = 0;
  }
  *(ushort4*)(Xd + (size_t)slot * ND + d) = u;
}

// ---------------- transpose+convert: W [E][K][N] fp32 -> Wt [E][N][K] bf16 ----------------
__global__ void transpose_kernel(const float* __restrict__ W, ushort_t* __restrict__ Wt,
                                 int K, int N) {
  __shared__ float tile[64][65];
  int e = blockIdx.z;
  int n0 = blockIdx.x * 64, k0 = blockIdx.y * 64;
  const float* We = W + (size_t)e * K * N;
  ushort_t* Wte = Wt + (size_t)e * K * N;
  for (int i = threadIdx.x; i < 4096; i += 256) {
    int r = i >> 6, c = i & 63;
    tile[r][c] = We[(size_t)(k0 + r) * N + n0 + c];
  }
  __syncthreads();
  for (int i = threadIdx.x; i < 4096; i += 256) {
    int c = i >> 6, r = i & 63;
    Wte[(size_t)(n0 + c) * K + k0 + r] = f2bf(tile[r][c]);
  }
}

// ---------------- shared GEMM mainloop: C[128x128] += A[128xK] * B[128xK]^T ----------------
// A row-major [M][K], B row-major [N][K] (both bf16, stride K). LDS tiles [128][64] bf16
// with ((row&7)<<4) byte XOR swizzle; global source pre-swizzled (linear LDS dest for
// global_load_lds), swizzle applied again on ds_read.
__device__ __forceinline__ void gemm_mainloop(const ushort_t* __restrict__ A,
                                              const ushort_t* __restrict__ B, int K,
                                              int bm0, int bn0, char* smem,
                                              f32x4 acc[4][4]) {
  const int tid = threadIdx.x;
  const int lane = tid & 63, wid = tid >> 6;
  const int wr = wid >> 1, wc = wid & 1;
  const int lr = lane & 15, lq = lane >> 4;
  char* sA = smem;
  char* sB = smem + 16384;
  for (int k0 = 0; k0 < K; k0 += 64) {
#pragma unroll
    for (int r = 0; r < 4; ++r) {
      int o = r * 4096 + tid * 16;             // physical dest byte in 16KB region
      int row = o >> 7;                        // 0..127
      int linner = (o & 127) ^ ((row & 7) << 4);  // logical k-byte within row
      const char* srcA = (const char*)(A + (size_t)(bm0 + row) * K + k0) + linner;
      const char* srcB = (const char*)(B + (size_t)(bn0 + row) * K + k0) + linner;
      __builtin_amdgcn_global_load_lds((const __attribute__((address_space(1))) void*)srcA,
                                       (__attribute__((address_space(3))) void*)(sA + o),
                                       16, 0, 0);
      __builtin_amdgcn_global_load_lds((const __attribute__((address_space(1))) void*)srcB,
                                       (__attribute__((address_space(3))) void*)(sB + o),
                                       16, 0, 0);
    }
    __syncthreads();
#pragma unroll
    for (int kk = 0; kk < 2; ++kk) {
      const int kb = kk * 64 + lq * 16;
      bf16x8 av[4], bv[4];
#pragma unroll
      for (int m = 0; m < 4; ++m) {
        int row = wr * 64 + m * 16 + lr;
        int off = ((row << 7) + kb) ^ ((lr & 7) << 4);
        av[m] = *(const bf16x8*)(sA + off);
      }
#pragma unroll
      for (int n = 0; n < 4; ++n) {
        int row = wc * 64 + n * 16 + lr;
        int off = ((row << 7) + kb) ^ ((lr & 7) << 4);
        bv[n] = *(const bf16x8*)(sB + off);
      }
#pragma unroll
      for (int m = 0; m < 4; ++m)
#pragma unroll
        for (int n = 0; n < 4; ++n)
          acc[m][n] = __builtin_amdgcn_mfma_f32_16x16x32_bf16(av[m], bv[n], acc[m][n], 0, 0, 0);
    }
    __syncthreads();
  }
}

// ---------------- GEMM1: H = relu(Xd @ W1t^T + b1), bf16 out ----------------
__global__ __launch_bounds__(256) void gemm1_kernel(const ushort_t* __restrict__ Xd,
                                                    const ushort_t* __restrict__ W1t,
                                                    const float* __restrict__ b1,
                                                    ushort_t* __restrict__ H) {
  int e = blockIdx.z;
  int bm0 = blockIdx.y * 128, bn0 = blockIdx.x * 128;
  const ushort_t* A = Xd + (size_t)e * CAP * ND;
  const ushort_t* B = W1t + (size_t)e * NF * ND;
  __shared__ __align__(16) char smem[32768];
  f32x4 zero4 = {0.f, 0.f, 0.f, 0.f};
  f32x4 acc[4][4];
#pragma unroll
  for (int m = 0; m < 4; ++m)
#pragma unroll
    for (int n = 0; n < 4; ++n) acc[m][n] = zero4;
  gemm_mainloop(A, B, ND, bm0, bn0, smem, acc);
  const int lane = threadIdx.x & 63, wid = threadIdx.x >> 6;
  const int wr = wid >> 1, wc = wid & 1;
  const int lr = lane & 15, lq = lane >> 4;
  ushort_t* He = H + (size_t)e * CAP * NF;
#pragma unroll
  for (int m = 0; m < 4; ++m) {
#pragma unroll
    for (int n = 0; n < 4; ++n) {
      int col = bn0 + wc * 64 + n * 16 + lr;
      float bias = b1[(size_t)e * NF + col];
#pragma unroll
      for (int j = 0; j < 4; ++j) {
        int row = bm0 + wr * 64 + m * 16 + lq * 4 + j;
        float v = acc[m][n][j] + bias;
        v = fmaxf(v, 0.f);
        He[(size_t)row * NF + col] = f2bf(v);
      }
    }
  }
}

// ---------------- GEMM2: out[token] = (H @ W2t^T + b2) * tprob ----------------
__global__ __launch_bounds__(256) void gemm2_kernel(const ushort_t* __restrict__ H,
                                                    const ushort_t* __restrict__ W2t,
                                                    const float* __restrict__ b2,
                                                    const int* __restrict__ tslot,
                                                    const float* __restrict__ tprob,
                                                    float* __restrict__ out) {
  int e = blockIdx.z;
  int bm0 = blockIdx.y * 128, bn0 = blockIdx.x * 128;
  const ushort_t* A = H + (size_t)e * CAP * NF;
  const ushort_t* B = W2t + (size_t)e * ND * NF;
  __shared__ __align__(16) char smem[32768];
  f32x4 zero4 = {0.f, 0.f, 0.f, 0.f};
  f32x4 acc[4][4];
#pragma unroll
  for (int m = 0; m < 4; ++m)
#pragma unroll
    for (int n = 0; n < 4; ++n) acc[m][n] = zero4;
  gemm_mainloop(A, B, NF, bm0, bn0, smem, acc);
  const int lane = threadIdx.x & 63, wid = threadIdx.x >> 6;
  const int wr = wid >> 1, wc = wid & 1;
  const int lr = lane & 15, lq = lane >> 4;
#pragma unroll
  for (int m = 0; m < 4; ++m) {
#pragma unroll
    for (int n = 0; n < 4; ++n) {
      int col = bn0 + wc * 64 + n * 16 + lr;
      float bias = b2[(size_t)e * ND + col];
#pragma unroll
      for (int j = 0; j < 4; ++j) {
        int row = bm0 + wr * 64 + m * 16 + lq * 4 + j;
        int t = tslot[e * CAP + row];
        if (t >= 0) {
          out[(size_t)t * ND + col] = (acc[m][n][j] + bias) * tprob[t];
        }
      }
    }
  }
}

extern "C" void kernel_launch(void* const* d_in, const int* in_sizes, int n_in,
                              void* d_out, int out_size, void* d_ws, size_t ws_size,
                              hipStream_t stream) {
  const float* h  = (const float*)d_in[0];
  const float* gw = (const float*)d_in[1];
  const float* gb = (const float*)d_in[2];
  const float* w1 = (const float*)d_in[3];
  const float* b1 = (const float*)d_in[4];
  const float* w2 = (const float*)d_in[5];
  const float* b2 = (const float*)d_in[6];
  float* out = (float*)d_out;
  char* ws = (char*)d_ws;

  ushort_t* W1t = (ushort_t*)(ws + W1T_OFF);
  ushort_t* W2t = (ushort_t*)(ws + W2T_OFF);
  ushort_t* Xd  = (ushort_t*)(ws + XD_OFF);
  ushort_t* H   = (ushort_t*)(ws + H_OFF);
  int* eidx     = (int*)(ws + EIDX_OFF);
  float* tprob  = (float*)(ws + TPROB_OFF);
  int* tslot    = (int*)(ws + TSLOT_OFF);

  zero_kernel<<<1024, 256, 0, stream>>>(out, (long)out_size);
  route_kernel<<<NT / 4, 256, 0, stream>>>(h, gw, gb, eidx, tprob);
  scan_kernel<<<1, 1024, 0, stream>>>(eidx, tslot);
  gather_kernel<<<NE * CAP, 256, 0, stream>>>(h, tslot, Xd);
  transpose_kernel<<<dim3(NF / 64, ND / 64, NE), 256, 0, stream>>>(w1, W1t, ND, NF);
  transpose_kernel<<<dim3(ND / 64, NF / 64, NE), 256, 0, stream>>>(w2, W2t, NF, ND);
  gemm1_kernel<<<dim3(NF / 128, CAP / 128, NE), 256, 0, stream>>>(Xd, W1t, b1, H);
  gemm2_kernel<<<dim3(ND / 128, CAP / 128, NE), 256, 0, stream>>>(H, W2t, b2, tslot, tprob, out);
}

// Round 2
// 458.436 us; speedup vs baseline: 1.0225x; 1.0225x over previous
//
#include <hip/hip_runtime.h>

typedef unsigned short ushort_t;
typedef __attribute__((ext_vector_type(8))) __bf16 bf16x8;
typedef __attribute__((ext_vector_type(4))) float f32x4;

#define NT 8192     // tokens
#define NE 8        // experts
#define ND 1024     // model dim
#define NF 4096     // ffn dim
#define CAP 1280    // capacity per expert
#define KSPLIT 2    // split-K for GEMM2

// ws layout (bytes)
#define W1T_OFF 0u                       // 8*4096*1024*2 = 67108864
#define W2T_OFF 67108864u                // 67108864
#define XD_OFF  134217728u               // 10240*1024*2 = 20971520
#define H_OFF   155189248u               // 10240*4096*2 = 83886080
#define EIDX_OFF 239075328u              // 8192*4
#define TPROB_OFF 239108096u             // 8192*4
#define TSLOT_OFF 239140864u             // 10240*4  -> total 239181824

__device__ __forceinline__ unsigned short f2bf(float f) {
  unsigned int u = __float_as_uint(f);
  unsigned int r = (u + 0x7fffu + ((u >> 16) & 1u)) >> 16;
  return (unsigned short)r;
}

// ---------------- zero out ----------------
__global__ void zero_kernel(float* __restrict__ p, long n) {
  long i = (long)blockIdx.x * blockDim.x + threadIdx.x;
  long stride = (long)gridDim.x * blockDim.x;
  float4* p4 = (float4*)p;
  long n4 = n >> 2;
  for (long j = i; j < n4; j += stride) p4[j] = make_float4(0.f, 0.f, 0.f, 0.f);
}

// ---------------- routing: one wave per token ----------------
__global__ void route_kernel(const float* __restrict__ x, const float* __restrict__ gw,
                             const float* __restrict__ gb, int* __restrict__ eidx,
                             float* __restrict__ tprob) {
  int wid = threadIdx.x >> 6, lane = threadIdx.x & 63;
  int t = blockIdx.x * 4 + wid;
  const float4* xv = (const float4*)(x + (size_t)t * ND);
  float acc[NE];
#pragma unroll
  for (int e = 0; e < NE; ++e) acc[e] = 0.f;
#pragma unroll
  for (int c = 0; c < 4; ++c) {
    float4 xx = xv[lane * 4 + c];
#pragma unroll
    for (int e = 0; e < NE; ++e) {
      float4 wv = *(const float4*)(gw + (size_t)e * ND + lane * 16 + c * 4);
      acc[e] += xx.x * wv.x + xx.y * wv.y + xx.z * wv.z + xx.w * wv.w;
    }
  }
#pragma unroll
  for (int off = 32; off >= 1; off >>= 1) {
#pragma unroll
    for (int e = 0; e < NE; ++e) acc[e] += __shfl_xor(acc[e], off, 64);
  }
  if (lane == 0) {
    float l[NE];
#pragma unroll
    for (int e = 0; e < NE; ++e) l[e] = acc[e] + gb[e];
    float mx = l[0];
    int am = 0;
#pragma unroll
    for (int e = 1; e < NE; ++e) {
      if (l[e] > mx) { mx = l[e]; am = e; }   // first occurrence kept on ties
    }
    float s = 0.f;
#pragma unroll
    for (int e = 0; e < NE; ++e) s += __expf(l[e] - mx);
    eidx[t] = am;
    tprob[t] = 1.0f / s;   // softmax prob of the max logit
  }
}

// ---------------- capacity scan (single block, order-preserving, wave-shuffle) ----------------
__global__ void scan_kernel(const int* __restrict__ eidx, int* __restrict__ tslot) {
  __shared__ unsigned long long w0[16], w1[16];
  int tid = threadIdx.x;
  int lane = tid & 63, wid = tid >> 6;
  for (int i = tid; i < NE * CAP; i += 1024) tslot[i] = -1;
  int myE[8];
  unsigned long long a = 0, b = 0;
#pragma unroll
  for (int i = 0; i < 8; ++i) {
    int e = eidx[tid * 8 + i];
    myE[i] = e;
    if (e < 4) a += 1ULL << (16 * e);
    else       b += 1ULL << (16 * (e - 4));
  }
  // wave-level inclusive scan (packed 4x16-bit per u64)
  unsigned long long ia = a, ib = b;
#pragma unroll
  for (int off = 1; off < 64; off <<= 1) {
    unsigned long long pa = __shfl_up(ia, off, 64);
    unsigned long long pb = __shfl_up(ib, off, 64);
    if (lane >= off) { ia += pa; ib += pb; }
  }
  if (lane == 63) { w0[wid] = ia; w1[wid] = ib; }
  __syncthreads();
  if (wid == 0 && lane < 16) {
    unsigned long long va = w0[lane], vb = w1[lane];
#pragma unroll
    for (int off = 1; off < 16; off <<= 1) {
      unsigned long long pa = __shfl_up(va, off, 64);
      unsigned long long pb = __shfl_up(vb, off, 64);
      if (lane >= off) { va += pa; vb += pb; }
    }
    w0[lane] = va; w1[lane] = vb;   // inclusive wave totals
  }
  __syncthreads();
  unsigned long long ea = ia - a, eb = ib - b;  // thread-exclusive within wave
  if (wid > 0) { ea += w0[wid - 1]; eb += w1[wid - 1]; }
  int base[NE];
#pragma unroll
  for (int e = 0; e < 4; ++e) {
    base[e]     = (int)((ea >> (16 * e)) & 0xffffULL);
    base[4 + e] = (int)((eb >> (16 * e)) & 0xffffULL);
  }
#pragma unroll
  for (int i = 0; i < 8; ++i) {
    int t = tid * 8 + i;
    int e = myE[i];
    int p = base[e]++;
    if (p < CAP) tslot[e * CAP + p] = t;
  }
}

// ---------------- gather tokens -> bf16 dispatch buffer ----------------
__global__ void gather_kernel(const float* __restrict__ x, const int* __restrict__ tslot,
                              ushort_t* __restrict__ Xd) {
  int slot = blockIdx.x;
  int t = tslot[slot];
  int d = threadIdx.x * 4;
  ushort4 u;
  if (t >= 0) {
    float4 v = *(const float4*)(x + (size_t)t * ND + d);
    u.x = f2bf(v.x); u.y = f2bf(v.y); u.z = f2bf(v.z); u.w = f2bf(v.w);
  } else {
    u.x = 0; u.y = 0; u.z = 0; u.w = 0;
  }
  *(ushort4*)(Xd + (size_t)slot * ND + d) = u;
}

// ---------------- transpose+convert: W [E][K][N] fp32 -> Wt [E][N][K] bf16 ----------------
// float4 loads, ushort4 stores; LDS tile 64x65 (2-way bank aliasing max = free)
__global__ void transpose_kernel(const float* __restrict__ W, ushort_t* __restrict__ Wt,
                                 int K, int N) {
  __shared__ float tile[64][65];
  int e = blockIdx.z;
  int n0 = blockIdx.x * 64, k0 = blockIdx.y * 64;
  const float* We = W + (size_t)e * K * N;
  ushort_t* Wte = Wt + (size_t)e * K * N;
  for (int i = threadIdx.x; i < 1024; i += 256) {
    int r = i >> 4, c4 = (i & 15) << 2;
    float4 v = *(const float4*)(We + (size_t)(k0 + r) * N + n0 + c4);
    tile[r][c4] = v.x; tile[r][c4 + 1] = v.y; tile[r][c4 + 2] = v.z; tile[r][c4 + 3] = v.w;
  }
  __syncthreads();
  for (int i = threadIdx.x; i < 1024; i += 256) {
    int c = i >> 4, r4 = (i & 15) << 2;
    ushort4 u;
    u.x = f2bf(tile[r4][c]);     u.y = f2bf(tile[r4 + 1][c]);
    u.z = f2bf(tile[r4 + 2][c]); u.w = f2bf(tile[r4 + 3][c]);
    *(ushort4*)(Wte + (size_t)(n0 + c) * K + k0 + r4) = u;
  }
}

// ---------------- shared GEMM mainloop: C[128x128] += A[128xkLen] * B[128xkLen]^T ----------------
// A row-major [M][ld], B row-major [N][ld] (both bf16). LDS tiles [128][64] bf16
// with ((row&7)<<4) byte XOR swizzle; global source pre-swizzled (linear LDS dest for
// global_load_lds), swizzle applied again on ds_read.
__device__ __forceinline__ void gemm_mainloop(const ushort_t* __restrict__ A,
                                              const ushort_t* __restrict__ B,
                                              int kLen, int ld,
                                              int bm0, int bn0, char* smem,
                                              f32x4 acc[4][4]) {
  const int tid = threadIdx.x;
  const int lane = tid & 63, wid = tid >> 6;
  const int wr = wid >> 1, wc = wid & 1;
  const int lr = lane & 15, lq = lane >> 4;
  char* sA = smem;
  char* sB = smem + 16384;
  for (int k0 = 0; k0 < kLen; k0 += 64) {
#pragma unroll
    for (int r = 0; r < 4; ++r) {
      int o = r * 4096 + tid * 16;             // physical dest byte in 16KB region
      int row = o >> 7;                        // 0..127
      int linner = (o & 127) ^ ((row & 7) << 4);  // logical k-byte within row
      const char* srcA = (const char*)(A + (size_t)(bm0 + row) * ld + k0) + linner;
      const char* srcB = (const char*)(B + (size_t)(bn0 + row) * ld + k0) + linner;
      __builtin_amdgcn_global_load_lds((const __attribute__((address_space(1))) void*)srcA,
                                       (__attribute__((address_space(3))) void*)(sA + o),
                                       16, 0, 0);
      __builtin_amdgcn_global_load_lds((const __attribute__((address_space(1))) void*)srcB,
                                       (__attribute__((address_space(3))) void*)(sB + o),
                                       16, 0, 0);
    }
    __syncthreads();
#pragma unroll
    for (int kk = 0; kk < 2; ++kk) {
      const int kb = kk * 64 + lq * 16;
      bf16x8 av[4], bv[4];
#pragma unroll
      for (int m = 0; m < 4; ++m) {
        int row = wr * 64 + m * 16 + lr;
        int off = ((row << 7) + kb) ^ ((lr & 7) << 4);
        av[m] = *(const bf16x8*)(sA + off);
      }
#pragma unroll
      for (int n = 0; n < 4; ++n) {
        int row = wc * 64 + n * 16 + lr;
        int off = ((row << 7) + kb) ^ ((lr & 7) << 4);
        bv[n] = *(const bf16x8*)(sB + off);
      }
#pragma unroll
      for (int m = 0; m < 4; ++m)
#pragma unroll
        for (int n = 0; n < 4; ++n)
          acc[m][n] = __builtin_amdgcn_mfma_f32_16x16x32_bf16(av[m], bv[n], acc[m][n], 0, 0, 0);
    }
    __syncthreads();
  }
}

// ---------------- GEMM1: H = relu(Xd @ W1t^T + b1), bf16 out ----------------
__global__ __launch_bounds__(256) void gemm1_kernel(const ushort_t* __restrict__ Xd,
                                                    const ushort_t* __restrict__ W1t,
                                                    const float* __restrict__ b1,
                                                    ushort_t* __restrict__ H) {
  int e = blockIdx.z;
  int bm0 = blockIdx.y * 128, bn0 = blockIdx.x * 128;
  const ushort_t* A = Xd + (size_t)e * CAP * ND;
  const ushort_t* B = W1t + (size_t)e * NF * ND;
  __shared__ __align__(16) char smem[32768];
  f32x4 zero4 = {0.f, 0.f, 0.f, 0.f};
  f32x4 acc[4][4];
#pragma unroll
  for (int m = 0; m < 4; ++m)
#pragma unroll
    for (int n = 0; n < 4; ++n) acc[m][n] = zero4;
  gemm_mainloop(A, B, ND, ND, bm0, bn0, smem, acc);
  const int lane = threadIdx.x & 63, wid = threadIdx.x >> 6;
  const int wr = wid >> 1, wc = wid & 1;
  const int lr = lane & 15, lq = lane >> 4;
  ushort_t* He = H + (size_t)e * CAP * NF;
#pragma unroll
  for (int m = 0; m < 4; ++m) {
#pragma unroll
    for (int n = 0; n < 4; ++n) {
      int col = bn0 + wc * 64 + n * 16 + lr;
      float bias = b1[(size_t)e * NF + col];
#pragma unroll
      for (int j = 0; j < 4; ++j) {
        int row = bm0 + wr * 64 + m * 16 + lq * 4 + j;
        float v = acc[m][n][j] + bias;
        v = fmaxf(v, 0.f);
        He[(size_t)row * NF + col] = f2bf(v);
      }
    }
  }
}

// ---------------- GEMM2 (split-K): out[token] += (H @ W2t^T [+ b2]) * tprob ----------------
__global__ __launch_bounds__(256) void gemm2_kernel(const ushort_t* __restrict__ H,
                                                    const ushort_t* __restrict__ W2t,
                                                    const float* __restrict__ b2,
                                                    const int* __restrict__ tslot,
                                                    const float* __restrict__ tprob,
                                                    float* __restrict__ out) {
  int z = blockIdx.z;
  int e = z >> 1, s = z & 1;                 // expert, K-split
  int bm0 = blockIdx.y * 128, bn0 = blockIdx.x * 128;
  const int kOff = s * (NF / KSPLIT);
  const ushort_t* A = H + (size_t)e * CAP * NF + kOff;
  const ushort_t* B = W2t + (size_t)e * ND * NF + kOff;
  __shared__ __align__(16) char smem[32768];
  f32x4 zero4 = {0.f, 0.f, 0.f, 0.f};
  f32x4 acc[4][4];
#pragma unroll
  for (int m = 0; m < 4; ++m)
#pragma unroll
    for (int n = 0; n < 4; ++n) acc[m][n] = zero4;
  gemm_mainloop(A, B, NF / KSPLIT, NF, bm0, bn0, smem, acc);
  const int lane = threadIdx.x & 63, wid = threadIdx.x >> 6;
  const int wr = wid >> 1, wc = wid & 1;
  const int lr = lane & 15, lq = lane >> 4;
  float bias[4];
#pragma unroll
  for (int n = 0; n < 4; ++n)
    bias[n] = (s == 0) ? b2[(size_t)e * ND + bn0 + wc * 64 + n * 16 + lr] : 0.f;
#pragma unroll
  for (int m = 0; m < 4; ++m) {
#pragma unroll
    for (int j = 0; j < 4; ++j) {
      int row = bm0 + wr * 64 + m * 16 + lq * 4 + j;
      int t = tslot[e * CAP + row];
      if (t >= 0) {
        float p = tprob[t];
#pragma unroll
        for (int n = 0; n < 4; ++n) {
          int col = bn0 + wc * 64 + n * 16 + lr;
          unsafeAtomicAdd(&out[(size_t)t * ND + col], (acc[m][n][j] + bias[n]) * p);
        }
      }
    }
  }
}

extern "C" void kernel_launch(void* const* d_in, const int* in_sizes, int n_in,
                              void* d_out, int out_size, void* d_ws, size_t ws_size,
                              hipStream_t stream) {
  const float* h  = (const float*)d_in[0];
  const float* gw = (const float*)d_in[1];
  const float* gb = (const float*)d_in[2];
  const float* w1 = (const float*)d_in[3];
  const float* b1 = (const float*)d_in[4];
  const float* w2 = (const float*)d_in[5];
  const float* b2 = (const float*)d_in[6];
  float* out = (float*)d_out;
  char* ws = (char*)d_ws;

  ushort_t* W1t = (ushort_t*)(ws + W1T_OFF);
  ushort_t* W2t = (ushort_t*)(ws + W2T_OFF);
  ushort_t* Xd  = (ushort_t*)(ws + XD_OFF);
  ushort_t* H   = (ushort_t*)(ws + H_OFF);
  int* eidx     = (int*)(ws + EIDX_OFF);
  float* tprob  = (float*)(ws + TPROB_OFF);
  int* tslot    = (int*)(ws + TSLOT_OFF);

  zero_kernel<<<1024, 256, 0, stream>>>(out, (long)out_size);
  route_kernel<<<NT / 4, 256, 0, stream>>>(h, gw, gb, eidx, tprob);
  scan_kernel<<<1, 1024, 0, stream>>>(eidx, tslot);
  gather_kernel<<<NE * CAP, 256, 0, stream>>>(h, tslot, Xd);
  transpose_kernel<<<dim3(NF / 64, ND / 64, NE), 256, 0, stream>>>(w1, W1t, ND, NF);
  transpose_kernel<<<dim3(ND / 64, NF / 64, NE), 256, 0, stream>>>(w2, W2t, NF, ND);
  gemm1_kernel<<<dim3(NF / 128, CAP / 128, NE), 256, 0, stream>>>(Xd, W1t, b1, H);
  gemm2_kernel<<<dim3(ND / 128, CAP / 128, NE * KSPLIT), 256, 0, stream>>>(H, W2t, b2, tslot, tprob, out);
}

// Round 3
// 449.314 us; speedup vs baseline: 1.0433x; 1.0203x over previous
//
#include <hip/hip_runtime.h>

typedef unsigned short ushort_t;
typedef __attribute__((ext_vector_type(8))) __bf16 bf16x8;
typedef __attribute__((ext_vector_type(4))) float f32x4;

#define NT 8192     // tokens
#define NE 8        // experts
#define ND 1024     // model dim
#define NF 4096     // ffn dim
#define CAP 1280    // capacity per expert
#define KSPLIT 2    // split-K for GEMM2

// Blocked operand layout: per expert, elem (row, k) lives at
//   [(k>>6)][row][k&63]   (so one 128-row x 64-k tile = 16KB contiguous)

// ws layout (bytes)
#define W1T_OFF 0u                       // 8*4096*1024*2 = 67108864
#define W2T_OFF 67108864u                // 67108864
#define XD_OFF  134217728u               // 10240*1024*2 = 20971520
#define H_OFF   155189248u               // 10240*4096*2 = 83886080
#define EIDX_OFF 239075328u              // 8192*4
#define TPROB_OFF 239108096u             // 8192*4
#define TSLOT_OFF 239140864u             // 10240*4  -> total 239181824

__device__ __forceinline__ unsigned short f2bf(float f) {
  unsigned int u = __float_as_uint(f);
  unsigned int r = (u + 0x7fffu + ((u >> 16) & 1u)) >> 16;
  return (unsigned short)r;
}

// ---------------- zero out ----------------
__global__ void zero_kernel(float* __restrict__ p, long n) {
  long i = (long)blockIdx.x * blockDim.x + threadIdx.x;
  long stride = (long)gridDim.x * blockDim.x;
  float4* p4 = (float4*)p;
  long n4 = n >> 2;
  for (long j = i; j < n4; j += stride) p4[j] = make_float4(0.f, 0.f, 0.f, 0.f);
}

// ---------------- routing: one wave per token ----------------
__global__ void route_kernel(const float* __restrict__ x, const float* __restrict__ gw,
                             const float* __restrict__ gb, int* __restrict__ eidx,
                             float* __restrict__ tprob) {
  int wid = threadIdx.x >> 6, lane = threadIdx.x & 63;
  int t = blockIdx.x * 4 + wid;
  const float4* xv = (const float4*)(x + (size_t)t * ND);
  float acc[NE];
#pragma unroll
  for (int e = 0; e < NE; ++e) acc[e] = 0.f;
#pragma unroll
  for (int c = 0; c < 4; ++c) {
    float4 xx = xv[lane * 4 + c];
#pragma unroll
    for (int e = 0; e < NE; ++e) {
      float4 wv = *(const float4*)(gw + (size_t)e * ND + lane * 16 + c * 4);
      acc[e] += xx.x * wv.x + xx.y * wv.y + xx.z * wv.z + xx.w * wv.w;
    }
  }
#pragma unroll
  for (int off = 32; off >= 1; off >>= 1) {
#pragma unroll
    for (int e = 0; e < NE; ++e) acc[e] += __shfl_xor(acc[e], off, 64);
  }
  if (lane == 0) {
    float l[NE];
#pragma unroll
    for (int e = 0; e < NE; ++e) l[e] = acc[e] + gb[e];
    float mx = l[0];
    int am = 0;
#pragma unroll
    for (int e = 1; e < NE; ++e) {
      if (l[e] > mx) { mx = l[e]; am = e; }   // first occurrence kept on ties
    }
    float s = 0.f;
#pragma unroll
    for (int e = 0; e < NE; ++e) s += __expf(l[e] - mx);
    eidx[t] = am;
    tprob[t] = 1.0f / s;   // softmax prob of the max logit
  }
}

// ---------------- capacity scan (single block, order-preserving, wave-shuffle) ----------------
__global__ void scan_kernel(const int* __restrict__ eidx, int* __restrict__ tslot) {
  __shared__ unsigned long long w0[16], w1[16];
  int tid = threadIdx.x;
  int lane = tid & 63, wid = tid >> 6;
  for (int i = tid; i < NE * CAP; i += 1024) tslot[i] = -1;
  int myE[8];
  unsigned long long a = 0, b = 0;
#pragma unroll
  for (int i = 0; i < 8; ++i) {
    int e = eidx[tid * 8 + i];
    myE[i] = e;
    if (e < 4) a += 1ULL << (16 * e);
    else       b += 1ULL << (16 * (e - 4));
  }
  unsigned long long ia = a, ib = b;
#pragma unroll
  for (int off = 1; off < 64; off <<= 1) {
    unsigned long long pa = __shfl_up(ia, off, 64);
    unsigned long long pb = __shfl_up(ib, off, 64);
    if (lane >= off) { ia += pa; ib += pb; }
  }
  if (lane == 63) { w0[wid] = ia; w1[wid] = ib; }
  __syncthreads();
  if (wid == 0 && lane < 16) {
    unsigned long long va = w0[lane], vb = w1[lane];
#pragma unroll
    for (int off = 1; off < 16; off <<= 1) {
      unsigned long long pa = __shfl_up(va, off, 64);
      unsigned long long pb = __shfl_up(vb, off, 64);
      if (lane >= off) { va += pa; vb += pb; }
    }
    w0[lane] = va; w1[lane] = vb;
  }
  __syncthreads();
  unsigned long long ea = ia - a, eb = ib - b;
  if (wid > 0) { ea += w0[wid - 1]; eb += w1[wid - 1]; }
  int base[NE];
#pragma unroll
  for (int e = 0; e < 4; ++e) {
    base[e]     = (int)((ea >> (16 * e)) & 0xffffULL);
    base[4 + e] = (int)((eb >> (16 * e)) & 0xffffULL);
  }
#pragma unroll
  for (int i = 0; i < 8; ++i) {
    int t = tid * 8 + i;
    int e = myE[i];
    int p = base[e]++;
    if (p < CAP) tslot[e * CAP + p] = t;
  }
}

// ---------------- gather tokens -> bf16 dispatch buffer (blocked layout) ----------------
__global__ void gather_kernel(const float* __restrict__ x, const int* __restrict__ tslot,
                              ushort_t* __restrict__ Xd) {
  int slot = blockIdx.x;
  int e = slot / CAP, row = slot % CAP;
  int t = tslot[slot];
  int d = threadIdx.x * 4;
  ushort4 u;
  if (t >= 0) {
    float4 v = *(const float4*)(x + (size_t)t * ND + d);
    u.x = f2bf(v.x); u.y = f2bf(v.y); u.z = f2bf(v.z); u.w = f2bf(v.w);
  } else {
    u.x = 0; u.y = 0; u.z = 0; u.w = 0;
  }
  ushort_t* dst = Xd + (size_t)e * CAP * ND + (size_t)(d >> 6) * CAP * 64 + row * 64 + (d & 63);
  *(ushort4*)dst = u;
}

// ---------------- transpose+convert: W [E][K][N] fp32 -> Wt_b [E][K/64][N][64] bf16 ----------------
// Contiguous 16B stores; LDS tile 64x65.
__global__ void transpose_kernel(const float* __restrict__ W, ushort_t* __restrict__ Wt,
                                 int K, int N) {
  __shared__ float tile[64][65];
  int e = blockIdx.z;
  int n0 = blockIdx.x * 64, k0 = blockIdx.y * 64;
  const float* We = W + (size_t)e * K * N;
  ushort_t* Wte = Wt + (size_t)e * K * N + (size_t)(k0 >> 6) * N * 64;
  for (int i = threadIdx.x; i < 1024; i += 256) {
    int r = i >> 4, c4 = (i & 15) << 2;
    float4 v = *(const float4*)(We + (size_t)(k0 + r) * N + n0 + c4);
    tile[r][c4] = v.x; tile[r][c4 + 1] = v.y; tile[r][c4 + 2] = v.z; tile[r][c4 + 3] = v.w;
  }
  __syncthreads();
  for (int i = threadIdx.x; i < 512; i += 256) {
    int n = i >> 3, kq = (i & 7) << 3;
    uint4 u;
    u.x = (unsigned)f2bf(tile[kq + 0][n]) | ((unsigned)f2bf(tile[kq + 1][n]) << 16);
    u.y = (unsigned)f2bf(tile[kq + 2][n]) | ((unsigned)f2bf(tile[kq + 3][n]) << 16);
    u.z = (unsigned)f2bf(tile[kq + 4][n]) | ((unsigned)f2bf(tile[kq + 5][n]) << 16);
    u.w = (unsigned)f2bf(tile[kq + 6][n]) | ((unsigned)f2bf(tile[kq + 7][n]) << 16);
    *(uint4*)(Wte + (size_t)(n0 + n) * 64 + kq) = u;
  }
}

// ---------------- shared GEMM mainloop (blocked operands) ----------------
// A_b, B_b: blocked [kb][rows][64] bf16 (byte pointers). One K-step tile = 16KB contiguous.
// LDS tiles [128][64] bf16 with ((row&7)<<4) byte XOR swizzle; global source pre-swizzled
// (linear LDS dest for global_load_lds), swizzle applied again on ds_read.
__device__ __forceinline__ void gemm_mainloop(const char* __restrict__ Ab,
                                              const char* __restrict__ Bb,
                                              int kbStart, int kbEnd,
                                              size_t aBlkB, size_t bBlkB,
                                              int bm0, int bn0, char* smem,
                                              f32x4 acc[4][4]) {
  const int tid = threadIdx.x;
  const int lane = tid & 63, wid = tid >> 6;
  const int wr = wid >> 1, wc = wid & 1;
  const int lr = lane & 15, lq = lane >> 4;
  char* sA = smem;
  char* sB = smem + 16384;
  for (int kb = kbStart; kb < kbEnd; ++kb) {
    const char* bA = Ab + (size_t)kb * aBlkB + (size_t)bm0 * 128;
    const char* bB = Bb + (size_t)kb * bBlkB + (size_t)bn0 * 128;
#pragma unroll
    for (int r = 0; r < 4; ++r) {
      int o = r * 4096 + tid * 16;                      // physical dest byte
      int row = o >> 7;
      int src = (o & ~127) | ((o & 127) ^ ((row & 7) << 4));  // pre-swizzled global source
      __builtin_amdgcn_global_load_lds((const __attribute__((address_space(1))) void*)(bA + src),
                                       (__attribute__((address_space(3))) void*)(sA + o),
                                       16, 0, 0);
      __builtin_amdgcn_global_load_lds((const __attribute__((address_space(1))) void*)(bB + src),
                                       (__attribute__((address_space(3))) void*)(sB + o),
                                       16, 0, 0);
    }
    __syncthreads();
#pragma unroll
    for (int kk = 0; kk < 2; ++kk) {
      const int kbyte = kk * 64 + lq * 16;
      bf16x8 av[4], bv[4];
#pragma unroll
      for (int m = 0; m < 4; ++m) {
        int row = wr * 64 + m * 16 + lr;
        int off = ((row << 7) + kbyte) ^ ((lr & 7) << 4);
        av[m] = *(const bf16x8*)(sA + off);
      }
#pragma unroll
      for (int n = 0; n < 4; ++n) {
        int row = wc * 64 + n * 16 + lr;
        int off = ((row << 7) + kbyte) ^ ((lr & 7) << 4);
        bv[n] = *(const bf16x8*)(sB + off);
      }
#pragma unroll
      for (int m = 0; m < 4; ++m)
#pragma unroll
        for (int n = 0; n < 4; ++n)
          acc[m][n] = __builtin_amdgcn_mfma_f32_16x16x32_bf16(av[m], bv[n], acc[m][n], 0, 0, 0);
    }
    __syncthreads();
  }
}

// ---------------- GEMM1: H_b = relu(Xd_b @ W1t_b^T + b1), bf16 blocked out ----------------
__global__ __launch_bounds__(256) void gemm1_kernel(const ushort_t* __restrict__ Xd,
                                                    const ushort_t* __restrict__ W1t,
                                                    const float* __restrict__ b1,
                                                    ushort_t* __restrict__ H) {
  int e = blockIdx.z;
  int bm0 = blockIdx.y * 128, bn0 = blockIdx.x * 128;
  const char* A = (const char*)(Xd + (size_t)e * CAP * ND);
  const char* B = (const char*)(W1t + (size_t)e * NF * ND);
  __shared__ __align__(16) char smem[32768];
  f32x4 zero4 = {0.f, 0.f, 0.f, 0.f};
  f32x4 acc[4][4];
#pragma unroll
  for (int m = 0; m < 4; ++m)
#pragma unroll
    for (int n = 0; n < 4; ++n) acc[m][n] = zero4;
  gemm_mainloop(A, B, 0, ND / 64, (size_t)CAP * 128, (size_t)NF * 128, bm0, bn0, smem, acc);
  const int lane = threadIdx.x & 63, wid = threadIdx.x >> 6;
  const int wr = wid >> 1, wc = wid & 1;
  const int lr = lane & 15, lq = lane >> 4;
  ushort_t* He = H + (size_t)e * CAP * NF;
#pragma unroll
  for (int m = 0; m < 4; ++m) {
#pragma unroll
    for (int n = 0; n < 4; ++n) {
      int col = bn0 + wc * 64 + n * 16 + lr;
      float bias = b1[(size_t)e * NF + col];
      ushort_t* dst = He + (size_t)(col >> 6) * CAP * 64 + (col & 63);
#pragma unroll
      for (int j = 0; j < 4; ++j) {
        int row = bm0 + wr * 64 + m * 16 + lq * 4 + j;
        float v = acc[m][n][j] + bias;
        v = fmaxf(v, 0.f);
        dst[(size_t)row * 64] = f2bf(v);
      }
    }
  }
}

// ---------------- GEMM2 (split-K): out[token] += (H_b @ W2t_b^T [+ b2]) * tprob ----------------
__global__ __launch_bounds__(256) void gemm2_kernel(const ushort_t* __restrict__ H,
                                                    const ushort_t* __restrict__ W2t,
                                                    const float* __restrict__ b2,
                                                    const int* __restrict__ tslot,
                                                    const float* __restrict__ tprob,
                                                    float* __restrict__ out) {
  int z = blockIdx.z;
  int e = z >> 1, s = z & 1;
  int bm0 = blockIdx.y * 128, bn0 = blockIdx.x * 128;
  const char* A = (const char*)(H + (size_t)e * CAP * NF);
  const char* B = (const char*)(W2t + (size_t)e * ND * NF);
  __shared__ __align__(16) char smem[32768];
  f32x4 zero4 = {0.f, 0.f, 0.f, 0.f};
  f32x4 acc[4][4];
#pragma unroll
  for (int m = 0; m < 4; ++m)
#pragma unroll
    for (int n = 0; n < 4; ++n) acc[m][n] = zero4;
  const int kbHalf = NF / 64 / KSPLIT;   // 32
  gemm_mainloop(A, B, s * kbHalf, (s + 1) * kbHalf, (size_t)CAP * 128, (size_t)ND * 128,
                bm0, bn0, smem, acc);
  const int lane = threadIdx.x & 63, wid = threadIdx.x >> 6;
  const int wr = wid >> 1, wc = wid & 1;
  const int lr = lane & 15, lq = lane >> 4;
  float bias[4];
#pragma unroll
  for (int n = 0; n < 4; ++n)
    bias[n] = (s == 0) ? b2[(size_t)e * ND + bn0 + wc * 64 + n * 16 + lr] : 0.f;
#pragma unroll
  for (int m = 0; m < 4; ++m) {
#pragma unroll
    for (int j = 0; j < 4; ++j) {
      int row = bm0 + wr * 64 + m * 16 + lq * 4 + j;
      int t = tslot[e * CAP + row];
      if (t >= 0) {
        float p = tprob[t];
#pragma unroll
        for (int n = 0; n < 4; ++n) {
          int col = bn0 + wc * 64 + n * 16 + lr;
          unsafeAtomicAdd(&out[(size_t)t * ND + col], (acc[m][n][j] + bias[n]) * p);
        }
      }
    }
  }
}

extern "C" void kernel_launch(void* const* d_in, const int* in_sizes, int n_in,
                              void* d_out, int out_size, void* d_ws, size_t ws_size,
                              hipStream_t stream) {
  const float* h  = (const float*)d_in[0];
  const float* gw = (const float*)d_in[1];
  const float* gb = (const float*)d_in[2];
  const float* w1 = (const float*)d_in[3];
  const float* b1 = (const float*)d_in[4];
  const float* w2 = (const float*)d_in[5];
  const float* b2 = (const float*)d_in[6];
  float* out = (float*)d_out;
  char* ws = (char*)d_ws;

  ushort_t* W1t = (ushort_t*)(ws + W1T_OFF);
  ushort_t* W2t = (ushort_t*)(ws + W2T_OFF);
  ushort_t* Xd  = (ushort_t*)(ws + XD_OFF);
  ushort_t* H   = (ushort_t*)(ws + H_OFF);
  int* eidx     = (int*)(ws + EIDX_OFF);
  float* tprob  = (float*)(ws + TPROB_OFF);
  int* tslot    = (int*)(ws + TSLOT_OFF);

  zero_kernel<<<1024, 256, 0, stream>>>(out, (long)out_size);
  route_kernel<<<NT / 4, 256, 0, stream>>>(h, gw, gb, eidx, tprob);
  scan_kernel<<<1, 1024, 0, stream>>>(eidx, tslot);
  gather_kernel<<<NE * CAP, 256, 0, stream>>>(h, tslot, Xd);
  transpose_kernel<<<dim3(NF / 64, ND / 64, NE), 256, 0, stream>>>(w1, W1t, ND, NF);
  transpose_kernel<<<dim3(ND / 64, NF / 64, NE), 256, 0, stream>>>(w2, W2t, NF, ND);
  gemm1_kernel<<<dim3(NF / 128, CAP / 128, NE), 256, 0, stream>>>(Xd, W1t, b1, H);
  gemm2_kernel<<<dim3(ND / 128, CAP / 128, NE * KSPLIT), 256, 0, stream>>>(H, W2t, b2, tslot, tprob, out);
}

// Round 4
// 374.545 us; speedup vs baseline: 1.2515x; 1.1996x over previous
//
#include <hip/hip_runtime.h>

typedef unsigned short ushort_t;
typedef __attribute__((ext_vector_type(8))) __bf16 bf16x8;
typedef __attribute__((ext_vector_type(4))) float f32x4;

#define NT 8192     // tokens
#define NE 8        // experts
#define ND 1024     // model dim
#define NF 4096     // ffn dim
#define CAP 1280    // capacity per expert
#define KSPLIT 2    // split-K for GEMM2

// Blocked operand layout: per expert, elem (row, k) lives at
//   [(k>>6)][row][k&63]   (so one 128-row x 64-k tile = 16KB contiguous)

// ws layout (bytes)
#define W1T_OFF 0u                       // 8*4096*1024*2 = 67108864
#define W2T_OFF 67108864u                // 67108864
#define XD_OFF  134217728u               // 10240*1024*2 = 20971520
#define H_OFF   155189248u               // 10240*4096*2 = 83886080
#define EIDX_OFF 239075328u              // 8192*4
#define TPROB_OFF 239108096u             // 8192*4
#define TSLOT_OFF 239140864u             // 10240*4  -> total 239181824

__device__ __forceinline__ unsigned short f2bf(float f) {
  unsigned int u = __float_as_uint(f);
  unsigned int r = (u + 0x7fffu + ((u >> 16) & 1u)) >> 16;
  return (unsigned short)r;
}

// bijective XCD-chunked remap (m204): contiguous chunk of tiles per XCD
__device__ __forceinline__ int xcd_swizzle(int wgid, int nwg) {
  int q = nwg >> 3, r = nwg & 7;
  int xcd = wgid & 7, idx = wgid >> 3;
  return (xcd < r ? xcd * (q + 1) : r * (q + 1) + (xcd - r) * q) + idx;
}

// ---------------- zero out ----------------
__global__ void zero_kernel(float* __restrict__ p, long n) {
  long i = (long)blockIdx.x * blockDim.x + threadIdx.x;
  long stride = (long)gridDim.x * blockDim.x;
  float4* p4 = (float4*)p;
  long n4 = n >> 2;
  for (long j = i; j < n4; j += stride) p4[j] = make_float4(0.f, 0.f, 0.f, 0.f);
}

// ---------------- routing: one wave per token ----------------
__global__ void route_kernel(const float* __restrict__ x, const float* __restrict__ gw,
                             const float* __restrict__ gb, int* __restrict__ eidx,
                             float* __restrict__ tprob) {
  int wid = threadIdx.x >> 6, lane = threadIdx.x & 63;
  int t = blockIdx.x * 4 + wid;
  const float4* xv = (const float4*)(x + (size_t)t * ND);
  float acc[NE];
#pragma unroll
  for (int e = 0; e < NE; ++e) acc[e] = 0.f;
#pragma unroll
  for (int c = 0; c < 4; ++c) {
    float4 xx = xv[lane * 4 + c];
#pragma unroll
    for (int e = 0; e < NE; ++e) {
      float4 wv = *(const float4*)(gw + (size_t)e * ND + lane * 16 + c * 4);
      acc[e] += xx.x * wv.x + xx.y * wv.y + xx.z * wv.z + xx.w * wv.w;
    }
  }
#pragma unroll
  for (int off = 32; off >= 1; off >>= 1) {
#pragma unroll
    for (int e = 0; e < NE; ++e) acc[e] += __shfl_xor(acc[e], off, 64);
  }
  if (lane == 0) {
    float l[NE];
#pragma unroll
    for (int e = 0; e < NE; ++e) l[e] = acc[e] + gb[e];
    float mx = l[0];
    int am = 0;
#pragma unroll
    for (int e = 1; e < NE; ++e) {
      if (l[e] > mx) { mx = l[e]; am = e; }   // first occurrence kept on ties
    }
    float s = 0.f;
#pragma unroll
    for (int e = 0; e < NE; ++e) s += __expf(l[e] - mx);
    eidx[t] = am;
    tprob[t] = 1.0f / s;   // softmax prob of the max logit
  }
}

// ---------------- capacity scan (single block, order-preserving, wave-shuffle) ----------------
__global__ void scan_kernel(const int* __restrict__ eidx, int* __restrict__ tslot) {
  __shared__ unsigned long long w0[16], w1[16];
  int tid = threadIdx.x;
  int lane = tid & 63, wid = tid >> 6;
  for (int i = tid; i < NE * CAP; i += 1024) tslot[i] = -1;
  int myE[8];
  unsigned long long a = 0, b = 0;
#pragma unroll
  for (int i = 0; i < 8; ++i) {
    int e = eidx[tid * 8 + i];
    myE[i] = e;
    if (e < 4) a += 1ULL << (16 * e);
    else       b += 1ULL << (16 * (e - 4));
  }
  unsigned long long ia = a, ib = b;
#pragma unroll
  for (int off = 1; off < 64; off <<= 1) {
    unsigned long long pa = __shfl_up(ia, off, 64);
    unsigned long long pb = __shfl_up(ib, off, 64);
    if (lane >= off) { ia += pa; ib += pb; }
  }
  if (lane == 63) { w0[wid] = ia; w1[wid] = ib; }
  __syncthreads();
  if (wid == 0 && lane < 16) {
    unsigned long long va = w0[lane], vb = w1[lane];
#pragma unroll
    for (int off = 1; off < 16; off <<= 1) {
      unsigned long long pa = __shfl_up(va, off, 64);
      unsigned long long pb = __shfl_up(vb, off, 64);
      if (lane >= off) { va += pa; vb += pb; }
    }
    w0[lane] = va; w1[lane] = vb;
  }
  __syncthreads();
  unsigned long long ea = ia - a, eb = ib - b;
  if (wid > 0) { ea += w0[wid - 1]; eb += w1[wid - 1]; }
  int base[NE];
#pragma unroll
  for (int e = 0; e < 4; ++e) {
    base[e]     = (int)((ea >> (16 * e)) & 0xffffULL);
    base[4 + e] = (int)((eb >> (16 * e)) & 0xffffULL);
  }
#pragma unroll
  for (int i = 0; i < 8; ++i) {
    int t = tid * 8 + i;
    int e = myE[i];
    int p = base[e]++;
    if (p < CAP) tslot[e * CAP + p] = t;
  }
}

// ---------------- gather tokens -> bf16 dispatch buffer (blocked layout) ----------------
__global__ void gather_kernel(const float* __restrict__ x, const int* __restrict__ tslot,
                              ushort_t* __restrict__ Xd) {
  int slot = blockIdx.x;
  int e = slot / CAP, row = slot % CAP;
  int t = tslot[slot];
  int d = threadIdx.x * 4;
  ushort4 u;
  if (t >= 0) {
    float4 v = *(const float4*)(x + (size_t)t * ND + d);
    u.x = f2bf(v.x); u.y = f2bf(v.y); u.z = f2bf(v.z); u.w = f2bf(v.w);
  } else {
    u.x = 0; u.y = 0; u.z = 0; u.w = 0;
  }
  ushort_t* dst = Xd + (size_t)e * CAP * ND + (size_t)(d >> 6) * CAP * 64 + row * 64 + (d & 63);
  *(ushort4*)dst = u;
}

// ---------------- transpose+convert: W [E][K][N] fp32 -> Wt_b [E][K/64][N][64] bf16 ----------------
__global__ void transpose_kernel(const float* __restrict__ W, ushort_t* __restrict__ Wt,
                                 int K, int N) {
  __shared__ float tile[64][65];
  int e = blockIdx.z;
  int n0 = blockIdx.x * 64, k0 = blockIdx.y * 64;
  const float* We = W + (size_t)e * K * N;
  ushort_t* Wte = Wt + (size_t)e * K * N + (size_t)(k0 >> 6) * N * 64;
  for (int i = threadIdx.x; i < 1024; i += 256) {
    int r = i >> 4, c4 = (i & 15) << 2;
    float4 v = *(const float4*)(We + (size_t)(k0 + r) * N + n0 + c4);
    tile[r][c4] = v.x; tile[r][c4 + 1] = v.y; tile[r][c4 + 2] = v.z; tile[r][c4 + 3] = v.w;
  }
  __syncthreads();
  for (int i = threadIdx.x; i < 512; i += 256) {
    int n = i >> 3, kq = (i & 7) << 3;
    uint4 u;
    u.x = (unsigned)f2bf(tile[kq + 0][n]) | ((unsigned)f2bf(tile[kq + 1][n]) << 16);
    u.y = (unsigned)f2bf(tile[kq + 2][n]) | ((unsigned)f2bf(tile[kq + 3][n]) << 16);
    u.z = (unsigned)f2bf(tile[kq + 4][n]) | ((unsigned)f2bf(tile[kq + 5][n]) << 16);
    u.w = (unsigned)f2bf(tile[kq + 6][n]) | ((unsigned)f2bf(tile[kq + 7][n]) << 16);
    *(uint4*)(Wte + (size_t)(n0 + n) * 64 + kq) = u;
  }
}

// ---------------- GEMM mainloop: 2-phase double-buffered pipeline ----------------
// STAGE(t+1) issued BEFORE compute(t); single __syncthreads per K-step (its implicit
// vmcnt(0)+lgkmcnt(0) drain covers both the prefetch and the LDS reads).
// LDS: 2 buffers x (16KB A + 16KB B), ((row&7)<<4) XOR swizzle via pre-swizzled source.
__device__ __forceinline__ void gemm_mainloop(const char* __restrict__ Ab,
                                              const char* __restrict__ Bb,
                                              int kbStart, int kbEnd,
                                              size_t aBlkB, size_t bBlkB,
                                              int bm0, int bn0, char* smem,
                                              f32x4 acc[4][4]) {
  const int tid = threadIdx.x;
  const int lane = tid & 63, wid = tid >> 6;
  const int wr = wid >> 1, wc = wid & 1;
  const int lr = lane & 15, lq = lane >> 4;

  auto stage = [&](int kb, int buf) {
    const char* bA = Ab + (size_t)kb * aBlkB + (size_t)bm0 * 128;
    const char* bB = Bb + (size_t)kb * bBlkB + (size_t)bn0 * 128;
    char* sA = smem + buf * 32768;
    char* sB = sA + 16384;
#pragma unroll
    for (int r = 0; r < 4; ++r) {
      int o = r * 4096 + tid * 16;
      int row = o >> 7;
      int src = (o & ~127) | ((o & 127) ^ ((row & 7) << 4));
      __builtin_amdgcn_global_load_lds((const __attribute__((address_space(1))) void*)(bA + src),
                                       (__attribute__((address_space(3))) void*)(sA + o),
                                       16, 0, 0);
      __builtin_amdgcn_global_load_lds((const __attribute__((address_space(1))) void*)(bB + src),
                                       (__attribute__((address_space(3))) void*)(sB + o),
                                       16, 0, 0);
    }
  };

  stage(kbStart, 0);
  __syncthreads();                       // drains vmcnt(0): buf0 ready for all waves
  int cur = 0;
  for (int kb = kbStart; kb < kbEnd; ++kb) {
    if (kb + 1 < kbEnd) stage(kb + 1, cur ^ 1);   // prefetch overlaps compute below
    char* sA = smem + cur * 32768;
    char* sB = sA + 16384;
    __builtin_amdgcn_s_setprio(1);
#pragma unroll
    for (int kk = 0; kk < 2; ++kk) {
      const int kbyte = kk * 64 + lq * 16;
      bf16x8 av[4], bv[4];
#pragma unroll
      for (int m = 0; m < 4; ++m) {
        int row = wr * 64 + m * 16 + lr;
        int off = ((row << 7) + kbyte) ^ ((lr & 7) << 4);
        av[m] = *(const bf16x8*)(sA + off);
      }
#pragma unroll
      for (int n = 0; n < 4; ++n) {
        int row = wc * 64 + n * 16 + lr;
        int off = ((row << 7) + kbyte) ^ ((lr & 7) << 4);
        bv[n] = *(const bf16x8*)(sB + off);
      }
#pragma unroll
      for (int m = 0; m < 4; ++m)
#pragma unroll
        for (int n = 0; n < 4; ++n)
          acc[m][n] = __builtin_amdgcn_mfma_f32_16x16x32_bf16(av[m], bv[n], acc[m][n], 0, 0, 0);
    }
    __builtin_amdgcn_s_setprio(0);
    __syncthreads();                     // waits prefetch done + all reads of cur consumed
    cur ^= 1;
  }
}

// ---------------- GEMM1: H_b = relu(Xd_b @ W1t_b^T + b1), bf16 blocked out ----------------
__global__ __launch_bounds__(256) void gemm1_kernel(const ushort_t* __restrict__ Xd,
                                                    const ushort_t* __restrict__ W1t,
                                                    const float* __restrict__ b1,
                                                    ushort_t* __restrict__ H) {
  // XCD-chunked: each XCD owns exactly one expert (320 tiles); M-tile fastest
  // => Xd expert (2.6MB) L2-resident, W1t B-panels shared by 10 consecutive blocks.
  int swz = xcd_swizzle(blockIdx.x, (NF / 128) * (CAP / 128) * NE);
  int e = swz / ((NF / 128) * (CAP / 128));
  int rem = swz % ((NF / 128) * (CAP / 128));
  int bn0 = (rem / (CAP / 128)) * 128;
  int bm0 = (rem % (CAP / 128)) * 128;
  const char* A = (const char*)(Xd + (size_t)e * CAP * ND);
  const char* B = (const char*)(W1t + (size_t)e * NF * ND);
  __shared__ __align__(16) char smem[65536];
  f32x4 zero4 = {0.f, 0.f, 0.f, 0.f};
  f32x4 acc[4][4];
#pragma unroll
  for (int m = 0; m < 4; ++m)
#pragma unroll
    for (int n = 0; n < 4; ++n) acc[m][n] = zero4;
  gemm_mainloop(A, B, 0, ND / 64, (size_t)CAP * 128, (size_t)NF * 128, bm0, bn0, smem, acc);
  const int lane = threadIdx.x & 63, wid = threadIdx.x >> 6;
  const int wr = wid >> 1, wc = wid & 1;
  const int lr = lane & 15, lq = lane >> 4;
  ushort_t* He = H + (size_t)e * CAP * NF;
#pragma unroll
  for (int m = 0; m < 4; ++m) {
#pragma unroll
    for (int n = 0; n < 4; ++n) {
      int col = bn0 + wc * 64 + n * 16 + lr;
      float bias = b1[(size_t)e * NF + col];
      ushort_t* dst = He + (size_t)(col >> 6) * CAP * 64 + (col & 63);
#pragma unroll
      for (int j = 0; j < 4; ++j) {
        int row = bm0 + wr * 64 + m * 16 + lq * 4 + j;
        float v = acc[m][n][j] + bias;
        v = fmaxf(v, 0.f);
        dst[(size_t)row * 64] = f2bf(v);
      }
    }
  }
}

// ---------------- GEMM2 (split-K): out[token] += (H_b @ W2t_b^T [+ b2]) * tprob ----------------
__global__ __launch_bounds__(256) void gemm2_kernel(const ushort_t* __restrict__ H,
                                                    const ushort_t* __restrict__ W2t,
                                                    const float* __restrict__ b2,
                                                    const int* __restrict__ tslot,
                                                    const float* __restrict__ tprob,
                                                    float* __restrict__ out) {
  // XCD-chunked: each XCD owns 2 (expert,split) groups of 80 tiles; N-tile fastest
  // => 8 consecutive blocks share a 512KB A-panel.
  int swz = xcd_swizzle(blockIdx.x, (ND / 128) * (CAP / 128) * NE * KSPLIT);
  int z = swz / ((ND / 128) * (CAP / 128));
  int rem = swz % ((ND / 128) * (CAP / 128));
  int e = z >> 1, s = z & 1;
  int bm0 = (rem / (ND / 128)) * 128;
  int bn0 = (rem % (ND / 128)) * 128;
  const char* A = (const char*)(H + (size_t)e * CAP * NF);
  const char* B = (const char*)(W2t + (size_t)e * ND * NF);
  __shared__ __align__(16) char smem[65536];
  f32x4 zero4 = {0.f, 0.f, 0.f, 0.f};
  f32x4 acc[4][4];
#pragma unroll
  for (int m = 0; m < 4; ++m)
#pragma unroll
    for (int n = 0; n < 4; ++n) acc[m][n] = zero4;
  const int kbHalf = NF / 64 / KSPLIT;   // 32
  gemm_mainloop(A, B, s * kbHalf, (s + 1) * kbHalf, (size_t)CAP * 128, (size_t)ND * 128,
                bm0, bn0, smem, acc);
  const int lane = threadIdx.x & 63, wid = threadIdx.x >> 6;
  const int wr = wid >> 1, wc = wid & 1;
  const int lr = lane & 15, lq = lane >> 4;
  float bias[4];
#pragma unroll
  for (int n = 0; n < 4; ++n)
    bias[n] = (s == 0) ? b2[(size_t)e * ND + bn0 + wc * 64 + n * 16 + lr] : 0.f;
#pragma unroll
  for (int m = 0; m < 4; ++m) {
#pragma unroll
    for (int j = 0; j < 4; ++j) {
      int row = bm0 + wr * 64 + m * 16 + lq * 4 + j;
      int t = tslot[e * CAP + row];
      if (t >= 0) {
        float p = tprob[t];
#pragma unroll
        for (int n = 0; n < 4; ++n) {
          int col = bn0 + wc * 64 + n * 16 + lr;
          unsafeAtomicAdd(&out[(size_t)t * ND + col], (acc[m][n][j] + bias[n]) * p);
        }
      }
    }
  }
}

extern "C" void kernel_launch(void* const* d_in, const int* in_sizes, int n_in,
                              void* d_out, int out_size, void* d_ws, size_t ws_size,
                              hipStream_t stream) {
  const float* h  = (const float*)d_in[0];
  const float* gw = (const float*)d_in[1];
  const float* gb = (const float*)d_in[2];
  const float* w1 = (const float*)d_in[3];
  const float* b1 = (const float*)d_in[4];
  const float* w2 = (const float*)d_in[5];
  const float* b2 = (const float*)d_in[6];
  float* out = (float*)d_out;
  char* ws = (char*)d_ws;

  ushort_t* W1t = (ushort_t*)(ws + W1T_OFF);
  ushort_t* W2t = (ushort_t*)(ws + W2T_OFF);
  ushort_t* Xd  = (ushort_t*)(ws + XD_OFF);
  ushort_t* H   = (ushort_t*)(ws + H_OFF);
  int* eidx     = (int*)(ws + EIDX_OFF);
  float* tprob  = (float*)(ws + TPROB_OFF);
  int* tslot    = (int*)(ws + TSLOT_OFF);

  zero_kernel<<<1024, 256, 0, stream>>>(out, (long)out_size);
  route_kernel<<<NT / 4, 256, 0, stream>>>(h, gw, gb, eidx, tprob);
  scan_kernel<<<1, 1024, 0, stream>>>(eidx, tslot);
  gather_kernel<<<NE * CAP, 256, 0, stream>>>(h, tslot, Xd);
  transpose_kernel<<<dim3(NF / 64, ND / 64, NE), 256, 0, stream>>>(w1, W1t, ND, NF);
  transpose_kernel<<<dim3(ND / 64, NF / 64, NE), 256, 0, stream>>>(w2, W2t, NF, ND);
  gemm1_kernel<<<(NF / 128) * (CAP / 128) * NE, 256, 0, stream>>>(Xd, W1t, b1, H);
  gemm2_kernel<<<(ND / 128) * (CAP / 128) * NE * KSPLIT, 256, 0, stream>>>(H, W2t, b2, tslot, tprob, out);
}